// Round 5
// baseline (129.468 us; speedup 1.0000x reference)
//
#include <hip/hip_runtime.h>

// NMS filter: B=8, C=20, N=2048.
// R5: adj_kernel unchanged (per-batch sparse IoU adjacency, divide-free exact
// predicate). prop_kernel rebuilt: one-time LDS-resident CSR of HIGHER-KEY
// neighbors only (mean ~3/node), then fixpoint rounds touch LDS bytes only.
// Fallback to global-walk if edge count exceeds LDS cap (never for this data).

#define BB   8
#define CC   20
#define NBOX 2048
#define CAP  64
#define MAXE 20480            // LDS edge cap (40 KB); expected ~6K
#define PRE_THR 0.005f
#define IOU_M 0x1.CCCCCDp-2   // double, exactly 30198989 * 2^-26

typedef unsigned long long u64;
typedef unsigned int u32;
typedef unsigned short u16;

__device__ __forceinline__ float area_rn(float x1, float y1, float x2, float y2) {
    return __fmul_rn(fmaxf(__fsub_rn(x2, x1), 0.f), fmaxf(__fsub_rn(y2, y1), 0.f));
}
// exact: equivalent to __fdiv_rn(inter,den) > 0.45f for den>0 finite
__device__ __forceinline__ bool iou_gt(float inter, float den) {
    return (double)inter > IOU_M * (double)den;
}

// ---------------- Kernel 1: per-batch adjacency lists (unchanged) ------------
__global__ __launch_bounds__(1024) void adj_kernel(const float4* __restrict__ bbs,
                                                   u32* __restrict__ deg,
                                                   u16* __restrict__ nbr) {
    const int batch = blockIdx.x >> 5;
    const int seg   = blockIdx.x & 31;
    const int lane  = threadIdx.x & 63;
    const int wv    = threadIdx.x >> 6;

    __shared__ float4 sbox[NBOX];  // 32 KB
    __shared__ float  sar[NBOX];   // 8 KB

    const float4* bp = bbs + (size_t)batch * NBOX;
    for (int n = threadIdx.x; n < NBOX; n += 1024) {
        float4 bv = bp[n];
        sbox[n] = bv;
        sar[n]  = area_rn(bv.x, bv.y, bv.z, bv.w);
    }
    __syncthreads();

    const int r0 = seg * 64 + wv * 4;
    float4 rb[4]; float ra[4]; u32 hits[4] = {0, 0, 0, 0};
    #pragma unroll
    for (int t = 0; t < 4; ++t) { rb[t] = sbox[r0 + t]; ra[t] = sar[r0 + t]; }

    #pragma unroll 4
    for (int k = 0; k < 32; ++k) {
        const int c = lane + (k << 6);
        const float4 cb = sbox[c];
        const float  ca = sar[c];
        #pragma unroll
        for (int t = 0; t < 4; ++t) {
            float iw = fmaxf(__fsub_rn(fminf(rb[t].z, cb.z), fmaxf(rb[t].x, cb.x)), 0.f);
            float ih = fmaxf(__fsub_rn(fminf(rb[t].w, cb.w), fmaxf(rb[t].y, cb.y)), 0.f);
            float inter = __fmul_rn(iw, ih);
            float den = fmaxf(__fsub_rn(__fadd_rn(ra[t], ca), inter), 1e-12f);
            if (c != r0 + t && iou_gt(inter, den)) hits[t] |= 1u << k;
        }
    }

    #pragma unroll
    for (int t = 0; t < 4; ++t) {
        const int i = r0 + t;
        int cnt = __popc(hits[t]);
        int ofs = cnt;
        #pragma unroll
        for (int d = 1; d < 64; d <<= 1) {
            int v = __shfl_up(ofs, d);
            if (lane >= d) ofs += v;
        }
        int total = __shfl(ofs, 63);
        ofs -= cnt;
        u16* row = nbr + ((size_t)batch * NBOX + i) * CAP;
        u32 h = hits[t];
        while (h) {
            int k = __ffs(h) - 1; h &= h - 1;
            if (ofs < CAP) row[ofs] = (u16)(lane + (k << 6));
            ++ofs;
        }
        if (lane == 0) deg[batch * NBOX + i] = (u32)min(total, CAP);
    }
}

// ---------------- Kernel 2: sort-free greedy NMS, LDS-CSR fixpoint -----------
// grid = 160, block = 256 (8 nodes/thread). state: 0 pending, 1 alive, 2 dead.
__global__ __launch_bounds__(256) void prop_kernel(const float* __restrict__ conf,
                                                   const u32* __restrict__ deg,
                                                   const u16* __restrict__ nbr,
                                                   float* __restrict__ out) {
    const int wg   = blockIdx.x;
    const int b    = wg / CC;
    const int base = wg * NBOX;
    const int tid  = threadIdx.x;
    const int lane = tid & 63;
    const int wv   = tid >> 6;

    __shared__ float          sconf[NBOX];                     // 8 KB
    __shared__ unsigned char  sstate[NBOX];                    // 2 KB
    __shared__ union { u16 edge[MAXE]; u64 skey[NBOX]; } e;    // 40 KB
    __shared__ int wtot[4];
    __shared__ int sflag;

    const u32* degb = deg + b * NBOX;
    const u16* nbrb = nbr + (size_t)b * NBOX * CAP;

    // ---- init: conf, pre-threshold state ----
    float cv[8]; int dreg[8];
    #pragma unroll
    for (int p = 0; p < 8; ++p) {
        const int i = tid + (p << 8);
        float c = conf[base + i];
        cv[p] = c;
        sconf[i] = c;
        dreg[p] = (int)degb[i];
        sstate[i] = (c > PRE_THR) ? 0 : 2;
    }
    if (tid == 0) sflag = 0;
    __syncthreads();

    // ---- count higher-key live neighbors per node (filter: key_j > key_i,
    //      skip pre-thresholded j). key compare: bits desc, tie idx asc. ----
    int hcnt[8]; u32 und = 0;
    #pragma unroll
    for (int p = 0; p < 8; ++p) {
        const int i = tid + (p << 8);
        int cnt = 0;
        if (sstate[i] == 0) {
            const u32 bi = __float_as_uint(cv[p]);
            const u16* row = nbrb + (size_t)i * CAP;
            for (int k = 0; k < dreg[p]; ++k) {
                const int j = row[k];
                if (sstate[j] != 2) {
                    const u32 bj = __float_as_uint(sconf[j]);
                    if (bj > bi || (bj == bi && j < i)) ++cnt;
                }
            }
            if (cnt == 0) sstate[i] = 1;      // no higher rival -> alive now
            else und |= 1u << p;
        }
        hcnt[p] = cnt;
    }

    // ---- block scan over per-thread edge counts ----
    int tsum = 0;
    #pragma unroll
    for (int p = 0; p < 8; ++p) tsum += hcnt[p];
    int incl = tsum;
    #pragma unroll
    for (int d = 1; d < 64; d <<= 1) {
        int v = __shfl_up(incl, d);
        if (lane >= d) incl += v;
    }
    if (lane == 63) wtot[wv] = incl;
    __syncthreads();
    int wbase = 0;
    for (int w = 0; w < wv; ++w) wbase += wtot[w];
    const int total = wtot[0] + wtot[1] + wtot[2] + wtot[3];
    int tbase = wbase + incl - tsum;          // exclusive base for this thread

    if (total <= MAXE) {
        // ---- write filtered edges into LDS CSR ----
        int soff[8];
        #pragma unroll
        for (int p = 0; p < 8; ++p) {
            soff[p] = tbase;
            if (hcnt[p]) {
                const int i = tid + (p << 8);
                const u32 bi = __float_as_uint(cv[p]);
                const u16* row = nbrb + (size_t)i * CAP;
                for (int k = 0; k < dreg[p]; ++k) {
                    const int j = row[k];
                    if (sstate[j] != 2) {
                        const u32 bj = __float_as_uint(sconf[j]);
                        if (bj > bi || (bj == bi && j < i)) e.edge[tbase++] = (u16)j;
                    }
                }
            }
        }
        __syncthreads();

        // ---- fixpoint rounds, LDS only ----
        while (true) {
            bool changed = false;
            #pragma unroll 1
            for (int it = 0; it < 2; ++it) {   // two sweeps per barrier round
                u32 m = und;
                while (m) {
                    const int p = __ffs(m) - 1; m &= m - 1;
                    const int i = tid + (p << 8);
                    bool any_alive = false, any_pend = false;
                    const int o = soff[p], n = hcnt[p];
                    for (int k = 0; k < n; ++k) {
                        const int st = sstate[e.edge[o + k]];
                        any_alive |= (st == 1);
                        any_pend  |= (st == 0);
                        if (any_alive) break;
                    }
                    if (any_alive || !any_pend) {
                        sstate[i] = any_alive ? 2 : 1;
                        und &= ~(1u << p);
                        changed = true;
                    }
                }
            }
            if (changed) sflag = 1;
            __syncthreads();
            const int f = sflag;
            __syncthreads();
            if (!f) break;
            if (tid == 0) sflag = 0;
            __syncthreads();
        }
    } else {
        // ---- fallback: global-row walk with full keys (never for this data) --
        #pragma unroll
        for (int p = 0; p < 8; ++p) {
            const int i = tid + (p << 8);
            e.skey[i] = ((u64)__float_as_uint(cv[p]) << 32) | (u32)(~i);
        }
        __syncthreads();
        while (true) {
            bool changed = false;
            u32 m = und;
            while (m) {
                const int p = __ffs(m) - 1; m &= m - 1;
                const int i = tid + (p << 8);
                const u64 ki = e.skey[i];
                const u16* row = nbrb + (size_t)i * CAP;
                int verdict = 1;
                for (int k = 0; k < dreg[p]; ++k) {
                    const int j = row[k];
                    if (e.skey[j] > ki) {
                        const int st = sstate[j];
                        if (st == 1) { verdict = 2; break; }
                        if (st == 0) verdict = 0;
                    }
                }
                if (verdict != 0) {
                    sstate[i] = (unsigned char)verdict;
                    und &= ~(1u << p);
                    changed = true;
                }
            }
            if (changed) sflag = 1;
            __syncthreads();
            const int f = sflag;
            __syncthreads();
            if (!f) break;
            if (tid == 0) sflag = 0;
            __syncthreads();
        }
    }

    // ---- output ----
    #pragma unroll
    for (int p = 0; p < 8; ++p) {
        const int i = tid + (p << 8);
        out[base + i] = (sstate[i] == 1) ? cv[p] : 0.f;
    }
}

// ---------------- Fallback (monolithic, used only if ws too small) -----------
#define NMS_THR 0.45f
__global__ __launch_bounds__(256) void nms_mono(const float* __restrict__ bbs,
                                                const float* __restrict__ conf,
                                                float* __restrict__ out) {
    const int wg   = blockIdx.x;
    const int b    = wg / CC;
    const int base = wg * NBOX;
    const int tid  = threadIdx.x;
    const int lane = tid & 63;
    const int wv   = tid >> 6;

    __shared__ union {
        u64 keys[NBOX];
        struct { float x1[NBOX], y1[NBOX], x2[NBOX], y2[NBOX]; } a;
    } u;
    __shared__ u64           Mcol[NBOX];
    __shared__ int           sidx[NBOX];
    __shared__ unsigned char skeep[NBOX];

    for (int n = tid; n < NBOX; n += 256) {
        float cvv = conf[base + n];
        u.keys[n] = ((u64)__float_as_uint(cvv) << 32) | (u32)(~n);
    }
    __syncthreads();
    for (int k = 2; k <= NBOX; k <<= 1)
        for (int j = k >> 1; j > 0; j >>= 1) {
            const int mask = j - 1;
            for (int t = tid; t < NBOX / 2; t += 256) {
                int i = ((t & ~mask) << 1) | (t & mask), ip = i + j;
                u64 a = u.keys[i], c2 = u.keys[ip];
                if ((a < c2) == ((i & k) == 0)) { u.keys[i] = c2; u.keys[ip] = a; }
            }
            __syncthreads();
        }
    u64 myk[8];
    #pragma unroll
    for (int p = 0; p < 8; ++p) myk[p] = u.keys[tid + p * 256];
    __syncthreads();
    #pragma unroll
    for (int p = 0; p < 8; ++p) {
        int r = tid + p * 256;
        u64 key = myk[p];
        int idx = (int)(~(u32)key) & (NBOX - 1);
        float cvv = __uint_as_float((u32)(key >> 32));
        float4 bv = ((const float4*)bbs)[b * NBOX + idx];
        u.a.x1[r] = bv.x; u.a.y1[r] = bv.y; u.a.x2[r] = bv.z; u.a.y2[r] = bv.w;
        sidx[r] = idx;
        skeep[r] = (cvv > PRE_THR) ? 1 : 0;
        out[base + idx] = cvv;
    }
    __syncthreads();
    for (int c = wv; c < NBOX / 64; c += 4) {
        int r = c * 64 + lane;
        float bx1 = u.a.x1[r], by1 = u.a.y1[r], bx2 = u.a.x2[r], by2 = u.a.y2[r];
        float bar = area_rn(bx1, by1, bx2, by2);
        u64 col = 0;
        for (int s = 1; s < 64; ++s) {
            int src = (lane + s) & 63;
            float px1 = __shfl(bx1, src), py1 = __shfl(by1, src);
            float px2 = __shfl(bx2, src), py2 = __shfl(by2, src);
            float par = area_rn(px1, py1, px2, py2);
            float iw = fmaxf(__fsub_rn(fminf(px2, bx2), fmaxf(px1, bx1)), 0.f);
            float ih = fmaxf(__fsub_rn(fminf(py2, by2), fmaxf(py1, by1)), 0.f);
            float inter = __fmul_rn(iw, ih);
            float den = fmaxf(__fsub_rn(__fadd_rn(bar, par), inter), 1e-12f);
            if ((__fdiv_rn(inter, den) > NMS_THR) && (src > lane)) col |= 1ull << src;
        }
        Mcol[r] = col;
    }
    __syncthreads();
    for (int cb = 0; cb < NBOX; cb += 64) {
        bool k0 = skeep[cb + lane] != 0;
        u64 alive = __ballot(k0);
        if (alive)
            for (int l = 0; l < 64; ++l) {
                u64 cl = Mcol[cb + l];
                u64 take = (u64)0 - ((alive >> l) & 1ull);
                alive &= ~(cl & take);
            }
        if (tid < 64) skeep[cb + lane] = (unsigned char)((alive >> lane) & 1ull);
        if (alive)
            for (int jb = cb + 64 + wv * 64; jb < NBOX; jb += 256) {
                int jj = jb + lane;
                bool jk = skeep[jj] != 0;
                if (__ballot(jk)) {
                    float jx1 = u.a.x1[jj], jy1 = u.a.y1[jj];
                    float jx2 = u.a.x2[jj], jy2 = u.a.y2[jj];
                    float jar = area_rn(jx1, jy1, jx2, jy2);
                    bool dead = false;
                    u64 m = alive;
                    while (m) {
                        int l = __ffsll(m) - 1; m &= m - 1;
                        int r = cb + l;
                        float px1 = u.a.x1[r], py1 = u.a.y1[r];
                        float px2 = u.a.x2[r], py2 = u.a.y2[r];
                        float par = area_rn(px1, py1, px2, py2);
                        float iw = fmaxf(__fsub_rn(fminf(px2, jx2), fmaxf(px1, jx1)), 0.f);
                        float ih = fmaxf(__fsub_rn(fminf(py2, jy2), fmaxf(py1, jy1)), 0.f);
                        float inter = __fmul_rn(iw, ih);
                        float den = fmaxf(__fsub_rn(__fadd_rn(par, jar), inter), 1e-12f);
                        dead = dead | (__fdiv_rn(inter, den) > NMS_THR);
                    }
                    if (jk && dead) skeep[jj] = 0;
                }
            }
        __syncthreads();
    }
    #pragma unroll
    for (int p = 0; p < 8; ++p) {
        int r = tid + p * 256;
        if (!skeep[r]) out[base + sidx[r]] = 0.0f;
    }
}

extern "C" void kernel_launch(void* const* d_in, const int* in_sizes, int n_in,
                              void* d_out, int out_size, void* d_ws, size_t ws_size,
                              hipStream_t stream) {
    const float* bbs  = (const float*)d_in[0];   // [B, N, 4]
    const float* conf = (const float*)d_in[1];   // [B, C, N]
    float* out = (float*)d_out;                  // [B, C, N]

    const size_t deg_bytes = (size_t)BB * NBOX * sizeof(u32);        // 64 KB
    const size_t nbr_bytes = (size_t)BB * NBOX * CAP * sizeof(u16);  // 2 MB
    if (ws_size >= deg_bytes + nbr_bytes) {
        u32* deg = (u32*)d_ws;
        u16* nbr = (u16*)((char*)d_ws + deg_bytes);
        adj_kernel<<<dim3(BB * 32), dim3(1024), 0, stream>>>((const float4*)bbs, deg, nbr);
        prop_kernel<<<dim3(BB * CC), dim3(256), 0, stream>>>(conf, deg, nbr, out);
    } else {
        nms_mono<<<dim3(BB * CC), dim3(256), 0, stream>>>(bbs, conf, out);
    }
}

// Round 6
// 112.491 us; speedup vs baseline: 1.1509x; 1.1509x over previous
//
#include <hip/hip_runtime.h>

// NMS filter: B=8, C=20, N=2048.
// R6: adj_kernel also writes compact nbr8[batch][node][8] (one uint4 per node).
// prop_kernel: one coalesced uint4 load per node -> register-packed higher-key
// neighbor list (<=8 slots, static unroll) -> LDS-byte-only fixpoint rounds.
// deg>8 spills to CAP=64 rows; >8 higher-key rivals -> per-round global walk.

#define BB   8
#define CC   20
#define NBOX 2048
#define CAP  64
#define PRE_THR 0.005f
#define IOU_M 0x1.CCCCCDp-2   // double, exactly 30198989 * 2^-26

typedef unsigned long long u64;
typedef unsigned int u32;
typedef unsigned short u16;

__device__ __forceinline__ float area_rn(float x1, float y1, float x2, float y2) {
    return __fmul_rn(fmaxf(__fsub_rn(x2, x1), 0.f), fmaxf(__fsub_rn(y2, y1), 0.f));
}
// exact: equivalent to __fdiv_rn(inter,den) > 0.45f for den>0 finite
__device__ __forceinline__ bool iou_gt(float inter, float den) {
    return (double)inter > IOU_M * (double)den;
}

// ---------------- Kernel 1: per-batch adjacency (big rows + compact nbr8) ----
__global__ __launch_bounds__(1024) void adj_kernel(const float4* __restrict__ bbs,
                                                   u32* __restrict__ deg,
                                                   u16* __restrict__ nbr,
                                                   u16* __restrict__ nbr8) {
    const int batch = blockIdx.x >> 5;
    const int seg   = blockIdx.x & 31;
    const int lane  = threadIdx.x & 63;
    const int wv    = threadIdx.x >> 6;

    __shared__ float4 sbox[NBOX];  // 32 KB
    __shared__ float  sar[NBOX];   // 8 KB

    const float4* bp = bbs + (size_t)batch * NBOX;
    for (int n = threadIdx.x; n < NBOX; n += 1024) {
        float4 bv = bp[n];
        sbox[n] = bv;
        sar[n]  = area_rn(bv.x, bv.y, bv.z, bv.w);
    }
    __syncthreads();

    const int r0 = seg * 64 + wv * 4;
    float4 rb[4]; float ra[4]; u32 hits[4] = {0, 0, 0, 0};
    #pragma unroll
    for (int t = 0; t < 4; ++t) { rb[t] = sbox[r0 + t]; ra[t] = sar[r0 + t]; }

    #pragma unroll 4
    for (int k = 0; k < 32; ++k) {
        const int c = lane + (k << 6);
        const float4 cb = sbox[c];
        const float  ca = sar[c];
        #pragma unroll
        for (int t = 0; t < 4; ++t) {
            float iw = fmaxf(__fsub_rn(fminf(rb[t].z, cb.z), fmaxf(rb[t].x, cb.x)), 0.f);
            float ih = fmaxf(__fsub_rn(fminf(rb[t].w, cb.w), fmaxf(rb[t].y, cb.y)), 0.f);
            float inter = __fmul_rn(iw, ih);
            float den = fmaxf(__fsub_rn(__fadd_rn(ra[t], ca), inter), 1e-12f);
            if (c != r0 + t && iou_gt(inter, den)) hits[t] |= 1u << k;
        }
    }

    #pragma unroll
    for (int t = 0; t < 4; ++t) {
        const int i = r0 + t;
        int cnt = __popc(hits[t]);
        int ofs = cnt;
        #pragma unroll
        for (int d = 1; d < 64; d <<= 1) {
            int v = __shfl_up(ofs, d);
            if (lane >= d) ofs += v;
        }
        int total = __shfl(ofs, 63);
        ofs -= cnt;
        u16* row  = nbr  + ((size_t)batch * NBOX + i) * CAP;
        u16* row8 = nbr8 + ((size_t)batch * NBOX + i) * 8;
        u32 h = hits[t];
        while (h) {
            int k = __ffs(h) - 1; h &= h - 1;
            u16 j = (u16)(lane + (k << 6));
            if (ofs < 8)   row8[ofs] = j;
            if (ofs < CAP) row[ofs]  = j;
            ++ofs;
        }
        if (lane == 0) deg[batch * NBOX + i] = (u32)min(total, CAP);
    }
}

// ---------------- Kernel 2: register-list fixpoint greedy NMS ----------------
// grid = 160, block = 256 (8 nodes/thread). state: 0 pending, 1 alive, 2 dead.
__global__ __launch_bounds__(256) void prop_kernel(const float* __restrict__ conf,
                                                   const u32* __restrict__ deg,
                                                   const u16* __restrict__ nbr,
                                                   const u16* __restrict__ nbr8,
                                                   float* __restrict__ out) {
    const int wg   = blockIdx.x;
    const int b    = wg / CC;
    const int base = wg * NBOX;
    const int tid  = threadIdx.x;

    __shared__ float         sconf[NBOX];   // 8 KB
    __shared__ unsigned char sstate[NBOX];  // 2 KB
    __shared__ int sflag;

    const u32*   degb = deg  + b * NBOX;
    const u16*   nbrb = nbr  + (size_t)b * NBOX * CAP;
    const uint4* n8b  = (const uint4*)nbr8 + (size_t)b * NBOX;

    // ---- init (issue all global loads up-front, independent) ----
    float cv[8]; int dreg[8]; uint4 nv[8];
    #pragma unroll
    for (int p = 0; p < 8; ++p) {
        const int i = tid + (p << 8);
        cv[p]   = conf[base + i];
        dreg[p] = (int)degb[i];
        nv[p]   = n8b[i];
    }
    #pragma unroll
    for (int p = 0; p < 8; ++p) {
        const int i = tid + (p << 8);
        sconf[i]  = cv[p];
        sstate[i] = (cv[p] > PRE_THR) ? 0 : 2;
    }
    if (tid == 0) sflag = 0;
    __syncthreads();

    // ---- build: pack higher-key live neighbors into 2x u64 per node ----
    u64 h0[8], h1[8]; u32 vm[8];     // packed indices + validity mask
    u32 und = 0, slow = 0;
    #pragma unroll
    for (int p = 0; p < 8; ++p) {
        h0[p] = 0; h1[p] = 0;
        const int i = tid + (p << 8);
        int cnt = 0;
        if (sstate[i] == 0) {
            const u32 bi = __float_as_uint(cv[p]);
            const int d  = dreg[p];
            const u32 w[4] = { nv[p].x, nv[p].y, nv[p].z, nv[p].w };
            #pragma unroll
            for (int k = 0; k < 8; ++k) {
                if (k < d) {
                    const int j = (int)((w[k >> 1] >> ((k & 1) << 4)) & 0xffff);
                    if (sstate[j] != 2) {
                        const u32 bj = __float_as_uint(sconf[j]);
                        if (bj > bi || (bj == bi && j < i)) {
                            if (cnt < 4)      h0[p] |= (u64)j << (cnt << 4);
                            else if (cnt < 8) h1[p] |= (u64)j << ((cnt - 4) << 4);
                            ++cnt;
                        }
                    }
                }
            }
            if (d > 8) {                                  // spill entries (rare)
                const u16* row = nbrb + (size_t)i * CAP;
                for (int k = 8; k < d; ++k) {
                    const int j = row[k];
                    if (sstate[j] != 2) {
                        const u32 bj = __float_as_uint(sconf[j]);
                        if (bj > bi || (bj == bi && j < i)) {
                            if (cnt < 4)      h0[p] |= (u64)j << (cnt << 4);
                            else if (cnt < 8) h1[p] |= (u64)j << ((cnt - 4) << 4);
                            ++cnt;
                        }
                    }
                }
            }
            if (cnt == 0) sstate[i] = 1;                  // no higher rival
            else {
                und |= 1u << p;
                if (cnt > 8) slow |= 1u << p;             // register list overflow
            }
        }
        vm[p] = (cnt >= 8) ? 0xffu : ((1u << cnt) - 1u);
    }
    __syncthreads();

    // ---- fixpoint rounds: 8 unconditional LDS byte reads per pending node ----
    while (true) {
        bool changed = false;
        #pragma unroll 1
        for (int sweep = 0; sweep < 2; ++sweep) {
            #pragma unroll
            for (int p = 0; p < 8; ++p) {
                if (und & (1u << p)) {
                    const int i = tid + (p << 8);
                    if (!(slow & (1u << p))) {
                        u32 alive_b = 0, pend_b = 0;
                        #pragma unroll
                        for (int k = 0; k < 4; ++k) {
                            const int j = (int)((h0[p] >> (k << 4)) & 0xffff);
                            const int st = sstate[j];
                            alive_b |= (u32)(st == 1) << k;
                            pend_b  |= (u32)(st == 0) << k;
                        }
                        #pragma unroll
                        for (int k = 0; k < 4; ++k) {
                            const int j = (int)((h1[p] >> (k << 4)) & 0xffff);
                            const int st = sstate[j];
                            alive_b |= (u32)(st == 1) << (k + 4);
                            pend_b  |= (u32)(st == 0) << (k + 4);
                        }
                        if (alive_b & vm[p]) {
                            sstate[i] = 2; und &= ~(1u << p); changed = true;
                        } else if (!(pend_b & vm[p])) {
                            sstate[i] = 1; und &= ~(1u << p); changed = true;
                        }
                    } else {
                        // slow path: walk full row from global (never for this data)
                        const u32 bi = __float_as_uint(cv[p]);
                        const u16* row = nbrb + (size_t)i * CAP;
                        int verdict = 1;
                        for (int k = 0; k < dreg[p]; ++k) {
                            const int j = row[k];
                            const int st = sstate[j];
                            if (st == 2) continue;
                            const u32 bj = __float_as_uint(sconf[j]);
                            if (bj > bi || (bj == bi && j < i)) {
                                if (st == 1) { verdict = 2; break; }
                                verdict = 0;
                            }
                        }
                        if (verdict != 0) {
                            sstate[i] = (unsigned char)verdict;
                            und &= ~(1u << p); changed = true;
                        }
                    }
                }
            }
        }
        if (changed) sflag = 1;
        __syncthreads();
        const int f = sflag;
        __syncthreads();
        if (!f) break;
        if (tid == 0) sflag = 0;
        __syncthreads();
    }

    // ---- output ----
    #pragma unroll
    for (int p = 0; p < 8; ++p) {
        const int i = tid + (p << 8);
        out[base + i] = (sstate[i] == 1) ? cv[p] : 0.f;
    }
}

// ---------------- Fallback (monolithic, used only if ws too small) -----------
#define NMS_THR 0.45f
__global__ __launch_bounds__(256) void nms_mono(const float* __restrict__ bbs,
                                                const float* __restrict__ conf,
                                                float* __restrict__ out) {
    const int wg   = blockIdx.x;
    const int b    = wg / CC;
    const int base = wg * NBOX;
    const int tid  = threadIdx.x;
    const int lane = tid & 63;
    const int wv   = tid >> 6;

    __shared__ union {
        u64 keys[NBOX];
        struct { float x1[NBOX], y1[NBOX], x2[NBOX], y2[NBOX]; } a;
    } u;
    __shared__ u64           Mcol[NBOX];
    __shared__ int           sidx[NBOX];
    __shared__ unsigned char skeep[NBOX];

    for (int n = tid; n < NBOX; n += 256) {
        float cvv = conf[base + n];
        u.keys[n] = ((u64)__float_as_uint(cvv) << 32) | (u32)(~n);
    }
    __syncthreads();
    for (int k = 2; k <= NBOX; k <<= 1)
        for (int j = k >> 1; j > 0; j >>= 1) {
            const int mask = j - 1;
            for (int t = tid; t < NBOX / 2; t += 256) {
                int i = ((t & ~mask) << 1) | (t & mask), ip = i + j;
                u64 a = u.keys[i], c2 = u.keys[ip];
                if ((a < c2) == ((i & k) == 0)) { u.keys[i] = c2; u.keys[ip] = a; }
            }
            __syncthreads();
        }
    u64 myk[8];
    #pragma unroll
    for (int p = 0; p < 8; ++p) myk[p] = u.keys[tid + p * 256];
    __syncthreads();
    #pragma unroll
    for (int p = 0; p < 8; ++p) {
        int r = tid + p * 256;
        u64 key = myk[p];
        int idx = (int)(~(u32)key) & (NBOX - 1);
        float cvv = __uint_as_float((u32)(key >> 32));
        float4 bv = ((const float4*)bbs)[b * NBOX + idx];
        u.a.x1[r] = bv.x; u.a.y1[r] = bv.y; u.a.x2[r] = bv.z; u.a.y2[r] = bv.w;
        sidx[r] = idx;
        skeep[r] = (cvv > PRE_THR) ? 1 : 0;
        out[base + idx] = cvv;
    }
    __syncthreads();
    for (int c = wv; c < NBOX / 64; c += 4) {
        int r = c * 64 + lane;
        float bx1 = u.a.x1[r], by1 = u.a.y1[r], bx2 = u.a.x2[r], by2 = u.a.y2[r];
        float bar = area_rn(bx1, by1, bx2, by2);
        u64 col = 0;
        for (int s = 1; s < 64; ++s) {
            int src = (lane + s) & 63;
            float px1 = __shfl(bx1, src), py1 = __shfl(by1, src);
            float px2 = __shfl(bx2, src), py2 = __shfl(by2, src);
            float par = area_rn(px1, py1, px2, py2);
            float iw = fmaxf(__fsub_rn(fminf(px2, bx2), fmaxf(px1, bx1)), 0.f);
            float ih = fmaxf(__fsub_rn(fminf(py2, by2), fmaxf(py1, by1)), 0.f);
            float inter = __fmul_rn(iw, ih);
            float den = fmaxf(__fsub_rn(__fadd_rn(bar, par), inter), 1e-12f);
            if ((__fdiv_rn(inter, den) > NMS_THR) && (src > lane)) col |= 1ull << src;
        }
        Mcol[r] = col;
    }
    __syncthreads();
    for (int cb = 0; cb < NBOX; cb += 64) {
        bool k0 = skeep[cb + lane] != 0;
        u64 alive = __ballot(k0);
        if (alive)
            for (int l = 0; l < 64; ++l) {
                u64 cl = Mcol[cb + l];
                u64 take = (u64)0 - ((alive >> l) & 1ull);
                alive &= ~(cl & take);
            }
        if (tid < 64) skeep[cb + lane] = (unsigned char)((alive >> lane) & 1ull);
        if (alive)
            for (int jb = cb + 64 + wv * 64; jb < NBOX; jb += 256) {
                int jj = jb + lane;
                bool jk = skeep[jj] != 0;
                if (__ballot(jk)) {
                    float jx1 = u.a.x1[jj], jy1 = u.a.y1[jj];
                    float jx2 = u.a.x2[jj], jy2 = u.a.y2[jj];
                    float jar = area_rn(jx1, jy1, jx2, jy2);
                    bool dead = false;
                    u64 m = alive;
                    while (m) {
                        int l = __ffsll(m) - 1; m &= m - 1;
                        int r = cb + l;
                        float px1 = u.a.x1[r], py1 = u.a.y1[r];
                        float px2 = u.a.x2[r], py2 = u.a.y2[r];
                        float par = area_rn(px1, py1, px2, py2);
                        float iw = fmaxf(__fsub_rn(fminf(px2, jx2), fmaxf(px1, jx1)), 0.f);
                        float ih = fmaxf(__fsub_rn(fminf(py2, jy2), fmaxf(py1, jy1)), 0.f);
                        float inter = __fmul_rn(iw, ih);
                        float den = fmaxf(__fsub_rn(__fadd_rn(par, jar), inter), 1e-12f);
                        dead = dead | (__fdiv_rn(inter, den) > NMS_THR);
                    }
                    if (jk && dead) skeep[jj] = 0;
                }
            }
        __syncthreads();
    }
    #pragma unroll
    for (int p = 0; p < 8; ++p) {
        int r = tid + p * 256;
        if (!skeep[r]) out[base + sidx[r]] = 0.0f;
    }
}

extern "C" void kernel_launch(void* const* d_in, const int* in_sizes, int n_in,
                              void* d_out, int out_size, void* d_ws, size_t ws_size,
                              hipStream_t stream) {
    const float* bbs  = (const float*)d_in[0];   // [B, N, 4]
    const float* conf = (const float*)d_in[1];   // [B, C, N]
    float* out = (float*)d_out;                  // [B, C, N]

    const size_t deg_bytes  = (size_t)BB * NBOX * sizeof(u32);        // 64 KB
    const size_t nbr_bytes  = (size_t)BB * NBOX * CAP * sizeof(u16);  // 2 MB
    const size_t nbr8_bytes = (size_t)BB * NBOX * 8 * sizeof(u16);    // 256 KB
    if (ws_size >= deg_bytes + nbr_bytes + nbr8_bytes) {
        u32* deg  = (u32*)d_ws;
        u16* nbr  = (u16*)((char*)d_ws + deg_bytes);
        u16* nbr8 = (u16*)((char*)d_ws + deg_bytes + nbr_bytes);
        adj_kernel<<<dim3(BB * 32), dim3(1024), 0, stream>>>((const float4*)bbs, deg, nbr, nbr8);
        prop_kernel<<<dim3(BB * CC), dim3(256), 0, stream>>>(conf, deg, nbr, nbr8, out);
    } else {
        nms_mono<<<dim3(BB * CC), dim3(256), 0, stream>>>(bbs, conf, out);
    }
}